// Round 1
// baseline (227.894 us; speedup 1.0000x reference)
//
#include <hip/hip_runtime.h>

// YOLO 1D (audio) detection decoder, CENTER_DURATION encoding.
// Input  x: [B=32, G=131072, F=8] fp32 (8 floats / cell, 32B-aligned)
// Output   : fragments [B, G, 7] fp32, then mask [B, G] fp32 (1.0/0.0),
//            concatenated flat in d_out (tuple return order).
//
// Memory-bound: 128 MiB in + 128 MiB out. Strategy:
//  - 1 thread per cell; two aligned float4 loads (L2 merges the stride-2
//    dwordx4 pattern — every byte fetched exactly once).
//  - fragments staged in LDS [256][7] (stride-7 dwords: 7 coprime 32 banks,
//    2-way wave64 aliasing = free), then written back as 7 fully-coalesced
//    stride-1 dword sweeps (64 consecutive dwords / wave-instruction).
//  - __fadd_rn/__fmul_rn block FMA contraction so rintf (round-nearest-even,
//    = jnp.round) sees bit-identical pre-round values vs the JAX reference.

constexpr int BLOCK = 256;
constexpr int F_OUT = 7;

__global__ __launch_bounds__(BLOCK) void yolo_decode_kernel(
    const float4* __restrict__ in,    // [total_cells * 2] float4
    float* __restrict__ frag,         // [total_cells * 7]
    float* __restrict__ mask_out,     // [total_cells]
    int g_mask,                       // G - 1 (G is a power of two)
    float cell_coef,                  // INPUT_LENGTH / G   (= 8.0f)
    float unbind_coef)                // INPUT_LENGTH       (= 1048576.0f)
{
    __shared__ float s_frag[BLOCK * F_OUT];

    const int tid       = threadIdx.x;
    const int cell_base = blockIdx.x * BLOCK;
    const int cell      = cell_base + tid;

    // 32 B per cell, 16B-aligned: two dwordx4 loads.
    const float4 a = in[(size_t)cell * 2];       // conf, x1, x2, x3
    const float4 b = in[(size_t)cell * 2 + 1];   // x4, x5, x6, x7

    const int   g = cell & g_mask;               // grid-cell index within batch row
    const bool  m = a.x >= 0.5f;

    const float center = __fmul_rn(__fadd_rn((float)g, a.y), cell_coef);
    const float halfd  = __fmul_rn(__fmul_rn(a.z, unbind_coef), 0.5f);
    const float s_val  = rintf(__fadd_rn(center, -halfd));   // v_rndne_f32 = jnp.round
    const float e_val  = rintf(__fadd_rn(center,  halfd));

    const float o[F_OUT] = { s_val, e_val, a.w, b.x, b.y, b.z, b.w };
    #pragma unroll
    for (int k = 0; k < F_OUT; ++k)
        s_frag[tid * F_OUT + k] = m ? o[k] : 0.0f;

    mask_out[cell] = m ? 1.0f : 0.0f;

    __syncthreads();

    // Coalesced write-back: 7 sweeps of 256 consecutive dwords.
    float* dst = frag + (size_t)cell_base * F_OUT;
    #pragma unroll
    for (int k = 0; k < F_OUT; ++k) {
        const int idx = k * BLOCK + tid;
        dst[idx] = s_frag[idx];
    }
}

extern "C" void kernel_launch(void* const* d_in, const int* in_sizes, int n_in,
                              void* d_out, int out_size, void* d_ws, size_t ws_size,
                              hipStream_t stream) {
    (void)n_in; (void)d_ws; (void)ws_size; (void)out_size;

    const float* x   = (const float*)d_in[0];
    float*       out = (float*)d_out;

    constexpr int F_IN        = 8;
    constexpr int G           = 131072;
    constexpr float INPUT_LEN = 1048576.0f;

    const int total_cells = in_sizes[0] / F_IN;          // 32 * 131072 = 4,194,304
    float* frag = out;                                   // [total_cells * 7]
    float* mask = out + (size_t)total_cells * F_OUT;     // [total_cells]

    const int blocks = total_cells / BLOCK;              // exact: 16384 blocks

    yolo_decode_kernel<<<blocks, BLOCK, 0, stream>>>(
        (const float4*)x, frag, mask,
        G - 1, INPUT_LEN / (float)G, INPUT_LEN);
}